// Round 8
// baseline (283.276 us; speedup 1.0000x reference)
//
#include <hip/hip_runtime.h>

// MHA: B=4, S=2048, D=1024, H=16, Hd=64, causal. fp32 in/out, bf16 MFMA compute.
// cast -> fused QKV gemm (Q scaled, K row-major, V transposed) -> flash attn
// (32x32 MFMA, register-P, single-buffered K/V with windowed staging, 4 blk/CU)
// -> out gemm (double-buffered LDS, 1 barrier/iter).

typedef float f32x4 __attribute__((ext_vector_type(4)));
typedef float f32x16 __attribute__((ext_vector_type(16)));
typedef short s16x8 __attribute__((ext_vector_type(8)));

#if __has_builtin(__builtin_amdgcn_exp2f)
#define EXP2(x) __builtin_amdgcn_exp2f(x)
#else
#define EXP2(x) exp2f(x)
#endif

// RNE float -> bf16 bits
__device__ __forceinline__ unsigned short f2bf(float f) {
  unsigned int u = __float_as_uint(f);
  u += 0x7fffu + ((u >> 16) & 1u);
  return (unsigned short)(u >> 16);
}

// pack two floats to bf16 pair, round-half-up
__device__ __forceinline__ unsigned int pk2bf(float f0, float f1) {
  return __builtin_amdgcn_perm(__float_as_uint(f1) + 0x8000u,
                               __float_as_uint(f0) + 0x8000u, 0x07060302u);
}

// pack two floats to bf16 pair, TRUNCATING (1 v_perm) — for P only
__device__ __forceinline__ unsigned int pk2bf_t(float f0, float f1) {
  return __builtin_amdgcn_perm(__float_as_uint(f1), __float_as_uint(f0), 0x07060302u);
}

// async global->LDS, 16 bytes per lane (wave-uniform LDS base + lane*16)
__device__ __forceinline__ void gl_lds16(const short* g, short* lds) {
  __builtin_amdgcn_global_load_lds(
      (const __attribute__((address_space(1))) unsigned int*)g,
      (__attribute__((address_space(3))) unsigned int*)lds, 16, 0, 0);
}

// ---------------- fp32 -> bf16 cast: X + all 4 weights, one dispatch ----------------
__global__ __launch_bounds__(256) void cvt_all(const float4* __restrict__ X,
                                               const float4* __restrict__ Wq,
                                               const float4* __restrict__ Wk,
                                               const float4* __restrict__ Wv,
                                               const float4* __restrict__ Wo,
                                               ushort4* __restrict__ xb,
                                               ushort4* __restrict__ wqkv,
                                               ushort4* __restrict__ wob) {
  const int NX = 8192 * 1024 / 4;
  const int NW = 1024 * 1024 / 4;
  const int NT = NX + 4 * NW;
  int i = blockIdx.x * blockDim.x + threadIdx.x;
  int stride = gridDim.x * blockDim.x;
  for (int idx = i; idx < NT; idx += stride) {
    const float4* s;
    ushort4* d;
    int off;
    if (idx < NX) {
      s = X; d = xb; off = idx;
    } else {
      int j = idx - NX;
      int w = j >> 18;
      off = j & (NW - 1);
      switch (w) {
        case 0: s = Wq; d = wqkv; break;
        case 1: s = Wk; d = wqkv + NW; break;
        case 2: s = Wv; d = wqkv + 2 * NW; break;
        default: s = Wo; d = wob; break;
      }
    }
    float4 f = s[off];
    ushort4 r;
    r.x = f2bf(f.x); r.y = f2bf(f.y); r.z = f2bf(f.z); r.w = f2bf(f.w);
    d[off] = r;
  }
}

// ---------------- GEMM: C[M,N] = A[M,K] * B[N,K]^T (both bf16 row-major) ----------------
// MODE 0: fp32 output to Cf.  MODE 1: QKV mode (Q scaled / K / V^T outputs).
// DBUF 1: double-buffered LDS, 1 barrier per K-iter (for low-block-count grids).
template <int MODE, int DBUF>
__global__ __launch_bounds__(256) void gemm_bt(const short* __restrict__ A,
                                               const short* __restrict__ B,
                                               float* __restrict__ Cf,
                                               short* __restrict__ q_o,
                                               short* __restrict__ k_o,
                                               short* __restrict__ vT_o,
                                               int M, int N, int K) {
  const int tid = threadIdx.x;
  const int wave = tid >> 6, lane = tid & 63;
  const int quad = lane >> 4, l15 = lane & 15;
  const int m0 = blockIdx.x * 128, n0 = blockIdx.y * 128;
  const int wm = (wave >> 1) * 64, wn = (wave & 1) * 64;

  __shared__ __align__(16) short As[(DBUF ? 2 : 1) * 8192];
  __shared__ __align__(16) short Bs[(DBUF ? 2 : 1) * 8192];

  const f32x4 z4 = {0.f, 0.f, 0.f, 0.f};
  f32x4 acc[4][4];
  for (int i = 0; i < 4; ++i)
    for (int j = 0; j < 4; ++j) acc[i][j] = z4;

  // staging coords
  const int c0 = wave * 4;
  const int r0 = c0 * 8 + (lane >> 3);
  const int cc8 = lane & 7;

  if (DBUF) {  // prologue: stage k0=0 into buf 0
    for (int i = 0; i < 4; ++i) {
      int r = r0 + i * 8;
      int c8 = cc8 ^ (r & 7);
      gl_lds16(A + (size_t)(m0 + r) * K + c8 * 8, As + (c0 + i) * 512 + lane * 8);
      gl_lds16(B + (size_t)(n0 + r) * K + c8 * 8, Bs + (c0 + i) * 512 + lane * 8);
    }
  }

  for (int k0 = 0; k0 < K; k0 += 64) {
    __syncthreads();
    const int cur = DBUF ? ((k0 >> 6) & 1) : 0;
    if (DBUF) {
      if (k0 + 64 < K) {  // stage next into alternate buffer; full iter to drain
        const int nxt = cur ^ 1;
        for (int i = 0; i < 4; ++i) {
          int r = r0 + i * 8;
          int c8 = cc8 ^ (r & 7);
          gl_lds16(A + (size_t)(m0 + r) * K + k0 + 64 + c8 * 8,
                   As + nxt * 8192 + (c0 + i) * 512 + lane * 8);
          gl_lds16(B + (size_t)(n0 + r) * K + k0 + 64 + c8 * 8,
                   Bs + nxt * 8192 + (c0 + i) * 512 + lane * 8);
        }
      }
    } else {
      for (int i = 0; i < 4; ++i) {
        int r = r0 + i * 8;
        int c8 = cc8 ^ (r & 7);
        gl_lds16(A + (size_t)(m0 + r) * K + k0 + c8 * 8, As + (c0 + i) * 512 + lane * 8);
        gl_lds16(B + (size_t)(n0 + r) * K + k0 + c8 * 8, Bs + (c0 + i) * 512 + lane * 8);
      }
      __syncthreads();
    }
    const short* Ac = As + cur * 8192;
    const short* Bc = Bs + cur * 8192;
    for (int kk = 0; kk < 64; kk += 32) {
      int c8b = (kk >> 3) + quad;
      s16x8 af[4], bfr[4];
      for (int mt = 0; mt < 4; ++mt) {
        int row = wm + mt * 16 + l15;
        af[mt] = *(const s16x8*)(Ac + row * 64 + ((c8b ^ (row & 7)) << 3));
      }
      for (int nt = 0; nt < 4; ++nt) {
        int row = wn + nt * 16 + l15;
        bfr[nt] = *(const s16x8*)(Bc + row * 64 + ((c8b ^ (row & 7)) << 3));
      }
      for (int mt = 0; mt < 4; ++mt)
        for (int nt = 0; nt < 4; ++nt)
          acc[mt][nt] = __builtin_amdgcn_mfma_f32_16x16x32_bf16(af[mt], bfr[nt],
                                                                acc[mt][nt], 0, 0, 0);
    }
  }

  if (MODE == 0) {
    for (int mt = 0; mt < 4; ++mt)
      for (int nt = 0; nt < 4; ++nt) {
        int col = n0 + wn + nt * 16 + l15;
        for (int r = 0; r < 4; ++r) {
          int row = m0 + wm + mt * 16 + quad * 4 + r;
          Cf[(size_t)row * N + col] = acc[mt][nt][r];
        }
      }
  } else {
    if (n0 < 1024) {  // Q, fold softmax scale * log2(e)
      const float scale = 0.18033688011112042f;  // 0.125 * log2(e)
      for (int mt = 0; mt < 4; ++mt)
        for (int nt = 0; nt < 4; ++nt) {
          int col = n0 + wn + nt * 16 + l15;
          for (int r = 0; r < 4; ++r) {
            int row = m0 + wm + mt * 16 + quad * 4 + r;
            ((unsigned short*)q_o)[(size_t)row * 1024 + col] = f2bf(acc[mt][nt][r] * scale);
          }
        }
    } else if (n0 < 2048) {  // K
      for (int mt = 0; mt < 4; ++mt)
        for (int nt = 0; nt < 4; ++nt) {
          int col = n0 - 1024 + wn + nt * 16 + l15;
          for (int r = 0; r < 4; ++r) {
            int row = m0 + wm + mt * 16 + quad * 4 + r;
            ((unsigned short*)k_o)[(size_t)row * 1024 + col] = f2bf(acc[mt][nt][r]);
          }
        }
    } else {  // V transposed: vT[((b*16+h)*64+d)*2048 + s], 4 consecutive s per lane
      for (int mt = 0; mt < 4; ++mt)
        for (int nt = 0; nt < 4; ++nt) {
          int col = n0 - 2048 + wn + nt * 16 + l15;
          int h = col >> 6, d = col & 63;
          int row0 = m0 + wm + mt * 16 + quad * 4;
          int b = row0 >> 11, s = row0 & 2047;
          uint2 pk;
          pk.x = pk2bf(acc[mt][nt][0], acc[mt][nt][1]);
          pk.y = pk2bf(acc[mt][nt][2], acc[mt][nt][3]);
          *(uint2*)((unsigned short*)vT_o + (((size_t)b * 16 + h) * 64 + d) * 2048 + s) = pk;
        }
    }
  }
}

// ---------------- flash attention: 32x32 MFMA, register-P, windowed single-buffer ----
// grid (64 bh, 16 y): qt = 15 - y (heavy first). 4 waves x 32 q. LDS = Ks 16K + VTs
// 16K = 32 KB -> 4 blocks/CU (launch_bounds(256,4)), 4 waves/SIMD for latency hiding.
// Windowed staging, 2 barriers/iter, each drains exactly one 16KB DMA:
//   b1 -> stage VTs(t)  [drains at b2; window = QK + softmax]
//   b2 -> stage Ks(t+1) [drains at next b1; window = PV]
__global__ __launch_bounds__(256, 4) void attn_kernel(const short* __restrict__ qb,
                                                      const short* __restrict__ kb,
                                                      const short* __restrict__ vT,
                                                      short* __restrict__ ob) {
  const int bh = blockIdx.x;
  const int qt = 15 - (int)blockIdx.y;
  const int tid = threadIdx.x;
  const int wave = tid >> 6, lane = tid & 63;
  const int l31 = lane & 31, h = lane >> 5;
  const int q0 = qt * 128;
  const size_t rowbase = (size_t)(bh >> 4) * 2048;
  const int hoff = (bh & 15) * 64;

  __shared__ __align__(16) short Ks[8192];   // 128 kv x 64 d, swizzled (16 KB)
  __shared__ __align__(16) short VTs[8192];  // 64 d x 128 kv, swizzled (16 KB)

  // staging coords: chunks c = wave*4+i, 512 shorts each
  const int kc = wave * 4;
  const int kr = kc * 8 + (lane >> 3);
  const short* ksrc = kb + (rowbase + kr) * 1024 + hoff + (((lane & 7) ^ (kr & 7)) << 3);
  const int vg = lane & 15;
  const short* vsrc_i[4];
#pragma unroll
  for (int i = 0; i < 4; ++i) {
    int d = (kc + i) * 4 + (lane >> 4);
    vsrc_i[i] = vT + ((size_t)bh * 64 + d) * 2048 + ((vg ^ (d & 7)) << 3);
  }

  // Q B-frags: lane(q=l31, d = ks*16 + h*8 + j)
  s16x8 qf[4];
  {
    const short* qrow = qb + (rowbase + q0 + wave * 32 + l31) * 1024 + hoff + h * 8;
#pragma unroll
    for (int k = 0; k < 4; ++k) qf[k] = *(const s16x8*)(qrow + k * 16);
  }

  // prologue: stage Ks(0)
#pragma unroll
  for (int i = 0; i < 4; ++i)
    gl_lds16(ksrc + i * 8 * 1024, Ks + (kc + i) * 512 + lane * 8);

  f32x16 oacc[2];  // O^T: [d-tile], col=q=l31, row_d=(e&3)+8*(e>>2)+4h+32dt
#pragma unroll
  for (int dt = 0; dt < 2; ++dt)
#pragma unroll
    for (int e = 0; e < 16; ++e) oacc[dt][e] = 0.f;
  float lacc = 0.f;
  const int kswz = l31 & 7;

  for (int t = 0; t <= qt; ++t) {
    __syncthreads();  // b1: drains Ks(t) DMA (staged during PV(t-1) / prologue)

    // stage VTs(t): buffer last read in PV(t-1) (done before b1); drains at b2
#pragma unroll
    for (int i = 0; i < 4; ++i)
      gl_lds16(vsrc_i[i] + t * 128, VTs + (kc + i) * 512 + lane * 8);

    // S^T = K * Q^T, 4 m-tiles of 32 kv, 2 groups to bound registers.
    // C-layout: col=q=l31, row_kv=(e&3)+8*(e>>2)+4h (+32m). Then exp2 + pack.
    unsigned int pp[4][8];
    float sum = 0.f;
#pragma unroll
    for (int g = 0; g < 2; ++g) {
      f32x16 s0, s1;
#pragma unroll
      for (int e = 0; e < 16; ++e) { s0[e] = 0.f; s1[e] = 0.f; }
#pragma unroll
      for (int ks = 0; ks < 4; ++ks) {
        int pos = ((ks << 1) + h) ^ kswz;
        s16x8 kf0 = *(const s16x8*)(Ks + ((2 * g) * 32 + l31) * 64 + (pos << 3));
        s16x8 kf1 = *(const s16x8*)(Ks + ((2 * g + 1) * 32 + l31) * 64 + (pos << 3));
        s0 = __builtin_amdgcn_mfma_f32_32x32x16_bf16(kf0, qf[ks], s0, 0, 0, 0);
        s1 = __builtin_amdgcn_mfma_f32_32x32x16_bf16(kf1, qf[ks], s1, 0, 0, 0);
      }
      if (t == qt) {  // causal mask on diagonal tile
        int qg = wave * 32 + l31;
#pragma unroll
        for (int e = 0; e < 16; ++e) {
          int rloc = (e & 3) + 8 * (e >> 2) + 4 * h;
          if ((2 * g) * 32 + rloc > qg) s0[e] = -1e30f;
          if ((2 * g + 1) * 32 + rloc > qg) s1[e] = -1e30f;
        }
      }
#pragma unroll
      for (int rg = 0; rg < 8; ++rg) {
        float a0 = EXP2(s0[2 * rg]), a1 = EXP2(s0[2 * rg + 1]);
        float b0 = EXP2(s1[2 * rg]), b1 = EXP2(s1[2 * rg + 1]);
        sum += (a0 + a1) + (b0 + b1);
        pp[2 * g][rg] = pk2bf_t(a0, a1);
        pp[2 * g + 1][rg] = pk2bf_t(b0, b1);
      }
    }
    lacc += sum;

    __syncthreads();  // b2: drains VTs(t); certifies all waves done reading Ks(t)

    if (t < qt) {  // stage Ks(t+1): safe after b2; drains at next b1 (window = PV)
      const short* ks = ksrc + (size_t)(t + 1) * 128 * 1024;
#pragma unroll
      for (int i = 0; i < 4; ++i)
        gl_lds16(ks + i * 8 * 1024, Ks + (kc + i) * 512 + lane * 8);
    }

    // O^T += V^T * P^T. B-frag(kv step s): lane(q=l31, kv=s*16+h*8+j).
    // One uint2 shfl_xor(32) exchange + selects per step.
#pragma unroll
    for (int s = 0; s < 8; ++s) {
      int m = s >> 1, base = (s & 1) * 4;
      unsigned int ax = pp[m][base + 0], ay = pp[m][base + 1];
      unsigned int bx = pp[m][base + 2], by = pp[m][base + 3];
      unsigned int sx = h ? ax : bx, sy = h ? ay : by;
      unsigned int rx = (unsigned int)__shfl_xor((int)sx, 32);
      unsigned int ry = (unsigned int)__shfl_xor((int)sy, 32);
      union { s16x8 v; unsigned int u[4]; } pf;
      pf.u[0] = h ? rx : ax;
      pf.u[1] = h ? ry : ay;
      pf.u[2] = h ? bx : rx;
      pf.u[3] = h ? by : ry;
#pragma unroll
      for (int dt = 0; dt < 2; ++dt) {
        int d = dt * 32 + l31;
        s16x8 vf = *(const s16x8*)(VTs + d * 128 + ((((s << 1) + h) ^ (d & 7)) << 3));
        oacc[dt] = __builtin_amdgcn_mfma_f32_32x32x16_bf16(vf, pf.v, oacc[dt], 0, 0, 0);
      }
    }
  }

  // epilogue: l across the two half-lanes, normalize, store O rows (8B stores)
  lacc += __shfl_xor(lacc, 32);
  float inv = 1.0f / lacc;
  size_t row = rowbase + q0 + wave * 32 + l31;
  unsigned short* orow = (unsigned short*)ob + row * 1024 + hoff;
#pragma unroll
  for (int dt = 0; dt < 2; ++dt)
#pragma unroll
    for (int rg = 0; rg < 4; ++rg) {
      int d = dt * 32 + rg * 8 + 4 * h;
      uint2 pk;
      pk.x = pk2bf(oacc[dt][rg * 4 + 0] * inv, oacc[dt][rg * 4 + 1] * inv);
      pk.y = pk2bf(oacc[dt][rg * 4 + 2] * inv, oacc[dt][rg * 4 + 3] * inv);
      *(uint2*)(orow + d) = pk;
    }
}

extern "C" void kernel_launch(void* const* d_in, const int* in_sizes, int n_in,
                              void* d_out, int out_size, void* d_ws, size_t ws_size,
                              hipStream_t stream) {
  const float* X  = (const float*)d_in[0];
  const float* Wq = (const float*)d_in[1];
  const float* Wk = (const float*)d_in[2];
  const float* Wv = (const float*)d_in[3];
  const float* Wo = (const float*)d_in[4];

  // workspace (bf16 shorts), 72 MB total; ob aliases xb (dead after QKV gemm)
  short* xb   = (short*)d_ws;                    // 8192x1024 (16 MB)
  short* wqkv = xb + (size_t)8192 * 1024;        // 3072x1024 ( 6 MB)
  short* wob  = wqkv + (size_t)3072 * 1024;      // 1024x1024 ( 2 MB)
  short* qb   = wob + (size_t)1024 * 1024;       // 8192x1024 (16 MB)
  short* kb   = qb + (size_t)8192 * 1024;        // 8192x1024 (16 MB)
  short* vT   = kb + (size_t)8192 * 1024;        // (4,16,64,2048) (16 MB)
  short* ob   = xb;

  const int MB = 8192;

  cvt_all<<<3072, 256, 0, stream>>>((const float4*)X, (const float4*)Wq, (const float4*)Wk,
                                    (const float4*)Wv, (const float4*)Wo, (ushort4*)xb,
                                    (ushort4*)wqkv, (ushort4*)wob);

  // fused QKV projection -> qb (scaled), kb, vT (2-barrier structure: many block
  // generations give inter-block overlap; dbuf would cost occupancy — m132)
  gemm_bt<1, 0><<<dim3(64, 24), 256, 0, stream>>>(xb, wqkv, nullptr, qb, kb, vT,
                                                  MB, 3072, 1024);

  // flash attention -> ob (bf16)
  attn_kernel<<<dim3(64, 16), 256, 0, stream>>>(qb, kb, vT, ob);

  // output projection -> fp32 d_out (dbuf: only 1 block generation, needs
  // internal pipelining)
  gemm_bt<0, 1><<<dim3(64, 8), 256, 0, stream>>>(ob, wob, (float*)d_out, nullptr, nullptr,
                                                 nullptr, MB, 1024, 1024);
}